// Round 8
// baseline (2891.836 us; speedup 1.0000x reference)
//
#include <hip/hip_runtime.h>

typedef unsigned short u16;
typedef __bf16 bf16x8 __attribute__((ext_vector_type(8)));
typedef float f32x4 __attribute__((ext_vector_type(4)));

#define DEVINL __device__ __forceinline__

DEVINL float bf2f(u16 u){ union{unsigned u32; float f;} v; v.u32=(unsigned)u<<16; return v.f; }
DEVINL u16 f2bf(float f){ union{float f; unsigned u;} v; v.f=f; return (u16)((v.u + 0x7FFFu + ((v.u>>16)&1u))>>16); }

DEVINL void gload16(const u16* g, u16* l){
  __builtin_amdgcn_global_load_lds((const __attribute__((address_space(1))) void*)g,
                                   (__attribute__((address_space(3))) void*)l, 16, 0, 0);
}

// dims
#define BB 16
#define TT 1024
#define SS 1025
#define DD 512
#define HH 8
#define FFD 2048
#define NLAYER 6
#define MROWS (BB*SS)      // 16400
#define MPAD  16512        // 129*128
#define MX    (BB*TT)      // 16384

// ---------------- weight conversion ----------------
__global__ __launch_bounds__(256) void cvt_k(const float* __restrict__ in, u16* __restrict__ out, int n4){
  int i = blockIdx.x*256 + threadIdx.x;
  if (i < n4){
    const float4 v = ((const float4*)in)[i];
    ushort4 o; o.x=f2bf(v.x); o.y=f2bf(v.y); o.z=f2bf(v.z); o.w=f2bf(v.w);
    ((ushort4*)out)[i] = o;
  }
}

__global__ __launch_bounds__(256) void cvt_pre_k(const float* __restrict__ in, u16* __restrict__ out){
  int i = blockIdx.x*256 + threadIdx.x; // 512*320
  if (i < 512*320){
    int r = i / 320, c = i - r*320;
    out[i] = (c < 306) ? f2bf(in[r*306 + c]) : (u16)0;
  }
}

// ---------------- preproc: build feats (bf16, 16384 x 320), emit pitch ----------------
__global__ __launch_bounds__(128) void prep_k(const float* __restrict__ x, u16* __restrict__ feats, float* __restrict__ pitch_out){
  int row = blockIdx.x;            // 0..16383  (b*1024 + t)
  int t = row & 1023;
  const float* xr = x + (size_t)row*291;
  float pitch = xr[0];
  if (threadIdx.x == 0) pitch_out[row] = pitch;
  for (int c = threadIdx.x; c < 320; c += 128){
    float v;
    if (c < 290) v = xr[1+c];
    else if (c < 306){
      int i = (c < 298) ? (c-290) : (c-298);
      float base = (c < 298) ? pitch : (float)t;
      int fi = i & 3;
      float f = (fi==0)?1.f:(fi==1)?0.1f:(fi==2)?0.01f:0.001f;
      float a = base * f;
      v = (i < 4) ? sinf(a) : cosf(a);
    }
    else v = 0.f;
    feats[(size_t)row*320 + c] = f2bf(v);
  }
}

// ---------------- assemble h from pre-proj + cls, zero pad rows ----------------
__global__ __launch_bounds__(256) void assemble_k(const float* __restrict__ t1, const float* __restrict__ cls,
                                                  float* __restrict__ h, u16* __restrict__ hb){
  int idx = blockIdx.x*256 + threadIdx.x;
  if (idx >= MPAD*DD) return;
  int r = idx >> 9, d = idx & 511;
  float v = 0.f;
  if (r < MROWS){
    int b = r / 1025, s = r - b*1025;
    v = (s < 1024) ? t1[((size_t)b*1024 + s)*512 + d] : cls[d];
  }
  h[idx] = v; hb[idx] = f2bf(v);
}

// ---------------- GEMM: C[M,N] = A[M,K](bf16) * W[N,K]^T + bias ----------------
// BM=128; BN in {64,128}; BK in {64,128}. XCD-bijective block swizzle (T1).
// T2 swizzle via pre-swizzled global source + swizzled LDS read (LDS linear
// for global_load_lds). BK=128 halves barrier count for BN=64 kernels.
template<int BN, int BK, bool RELU, bool WBF, bool WF32>
__global__ __launch_bounds__(256)
void gemm_k(const u16* __restrict__ A, const u16* __restrict__ W,
            const float* __restrict__ bias, u16* __restrict__ obf,
            float* __restrict__ of32, int N, int K, int gy)
{
  __shared__ u16 As[128*BK];
  __shared__ u16 Ws[BN*BK];
  constexpr int NREP = BN/32;        // col fragments per wave (wave covers BN/2 cols)
  constexpr int KK = BK/32;          // K32 sub-steps per tile
  constexpr int GR = BK/8;           // 16B granules per row
  constexpr int AR = (128*BK)/2048;  // A staging rounds
  constexpr int WR = (BN*BK)/2048;   // W staging rounds
  const int tid = threadIdx.x;
  const int lane = tid & 63, wave = tid >> 6;
  const int wr = wave >> 1, wc = wave & 1;
  const int lr = lane & 15;
  const int x7 = lane & 7;           // == fragment_row & 7 for this lane
  const int gbase = lane >> 4;       // column granule base within K32 block

  // bijective 8-XCD swizzle (m204)
  const int nwg = gridDim.x;
  const int id = blockIdx.x;
  const int q = nwg >> 3, r8 = nwg & 7;
  const int xcd = id & 7, pos = id >> 3;
  const int wgid = (xcd < r8 ? xcd*(q+1) : r8*(q+1) + (xcd-r8)*q) + pos;
  const int bx = wgid / gy, by = wgid - bx*gy;
  const int m0 = bx * 128, n0 = by * BN;

  // swizzled column offsets (elems) for each K32 half
  int colsw[KK];
#pragma unroll
  for (int kk=0; kk<KK; ++kk){
    int gk = kk*4 + gbase;
    colsw[kk] = ((gk & ~7) | ((gk & 7) ^ x7)) * 8;
  }

  int aoff[4], boff[NREP];
#pragma unroll
  for (int i=0;i<4;++i) aoff[i] = (wr*64 + i*16 + lr)*BK;
#pragma unroll
  for (int i=0;i<NREP;++i) boff[i] = (wc*(BN/2) + i*16 + lr)*BK;

  f32x4 acc[4][NREP];
#pragma unroll
  for (int n=0;n<NREP;++n){
    float bv = bias[n0 + wc*(BN/2) + n*16 + lr];
#pragma unroll
    for (int m=0;m<4;++m) acc[m][n] = (f32x4){bv,bv,bv,bv};
  }

  for (int k0=0; k0<K; k0+=BK) {
#pragma unroll
    for (int r=0;r<AR;++r){
      int cb = r*256 + wave*64;
      int chunk = cb + lane;
      int row = chunk / GR, gp = chunk & (GR-1);
      int kc = ((gp & ~7) | ((gp & 7) ^ (row & 7))) * 8;   // pre-swizzled source
      gload16(A + (size_t)(m0+row)*K + k0 + kc, &As[cb*8]);
    }
#pragma unroll
    for (int r=0;r<WR;++r){
      int cb = r*256 + wave*64;
      int chunk = cb + lane;
      int row = chunk / GR, gp = chunk & (GR-1);
      int kc = ((gp & ~7) | ((gp & 7) ^ (row & 7))) * 8;
      gload16(W + (size_t)(n0+row)*K + k0 + kc, &Ws[cb*8]);
    }
    __syncthreads();
#pragma unroll
    for (int kk=0; kk<KK; ++kk){
      bf16x8 af[4], bfr[NREP];
#pragma unroll
      for (int m=0;m<4;++m) af[m] = *(const bf16x8*)&As[aoff[m] + colsw[kk]];
#pragma unroll
      for (int n=0;n<NREP;++n) bfr[n] = *(const bf16x8*)&Ws[boff[n] + colsw[kk]];
#pragma unroll
      for (int m=0;m<4;++m)
#pragma unroll
        for (int n=0;n<NREP;++n)
          acc[m][n] = __builtin_amdgcn_mfma_f32_16x16x32_bf16(af[m], bfr[n], acc[m][n], 0,0,0);
    }
    __syncthreads();
  }

  const int orow = m0 + wr*64 + (lane>>4)*4;
  const int ocol = n0 + wc*(BN/2) + lr;
#pragma unroll
  for (int m=0;m<4;++m)
#pragma unroll
    for (int n=0;n<NREP;++n){
#pragma unroll
      for (int j=0;j<4;++j){
        float v = acc[m][n][j];
        if (RELU) v = fmaxf(v, 0.f);
        size_t idx = (size_t)(orow + m*16 + j) * N + (ocol + n*16);
        if (WBF) obf[idx] = f2bf(v);
        if (WF32) of32[idx] = v;
      }
    }
}

// ---------------- windowed attention: one wave per (b,h,q), q in [0,1023] ----------------
__global__ __launch_bounds__(256) void attn_win_k(const u16* __restrict__ qkv, u16* __restrict__ ao){
  int wid = blockIdx.x*4 + (threadIdx.x>>6);
  int lane = threadIdx.x & 63;
  int q = wid & 1023, bh = wid >> 10;
  int hh = bh & 7, b = bh >> 3;
  float qv = bf2f(qkv[((size_t)(b*1025+q))*1536 + hh*64 + lane]);
  float sc[7];
#pragma unroll
  for (int jj=0;jj<7;++jj){
    int j = q - 3 + jj;
    int jc = min(max(j,0),1024);
    float kv = bf2f(qkv[((size_t)(b*1025+jc))*1536 + 512 + hh*64 + lane]);
    float p = qv * kv;
#pragma unroll
    for (int o2=1;o2<64;o2<<=1) p += __shfl_xor(p, o2);
    sc[jj] = (j>=0 && j<=1024) ? p*0.125f : -1e30f;
  }
  float m = sc[0];
#pragma unroll
  for (int jj=1;jj<7;++jj) m = fmaxf(m, sc[jj]);
  float l = 0.f, pj[7];
#pragma unroll
  for (int jj=0;jj<7;++jj){ pj[jj] = expf(sc[jj]-m); l += pj[jj]; }
  float o = 0.f;
#pragma unroll
  for (int jj=0;jj<7;++jj){
    int jc = min(max(q-3+jj,0),1024);
    float vv = bf2f(qkv[((size_t)(b*1025+jc))*1536 + 1024 + hh*64 + lane]);
    o += pj[jj]*vv;
  }
  ao[((size_t)(b*1025+q))*512 + hh*64 + lane] = f2bf(o / l);
}

// ---------------- last-row (global) attention: one block per (b,h) ----------------
// wave-parallel: lane = d (coalesced rows), butterfly-reduce per key.
__global__ __launch_bounds__(256) void attn_last_k(const u16* __restrict__ qkv, u16* __restrict__ ao){
  int b = blockIdx.x >> 3, hh = blockIdx.x & 7;
  __shared__ float sc[1025];
  __shared__ float red[256];
  __shared__ float wred[4];
  __shared__ float opart[4][64];
  int t = threadIdx.x, w = t>>6, lane = t&63;
  size_t base = (size_t)(b*1025)*1536 + hh*64;
  float qv = bf2f(qkv[base + (size_t)1024*1536 + lane]);
  float lmax = -1e30f;
  for (int j = w; j < 1025; j += 4){
    float kv = bf2f(qkv[base + (size_t)j*1536 + 512 + lane]);
    float p = qv * kv;
#pragma unroll
    for (int o2=1;o2<64;o2<<=1) p += __shfl_xor(p, o2);
    p *= 0.125f;
    if (lane == 0) sc[j] = p;
    lmax = fmaxf(lmax, p);
  }
  if (lane == 0) wred[w] = lmax;
  __syncthreads();
  float m = fmaxf(fmaxf(wred[0],wred[1]), fmaxf(wred[2],wred[3]));
  float lsum = 0.f;
  for (int j = t; j < 1025; j += 256){ float p = expf(sc[j]-m); sc[j]=p; lsum += p; }
  red[t] = lsum; __syncthreads();
  for (int o2=128;o2;o2>>=1){ if (t<o2) red[t]+=red[t+o2]; __syncthreads(); }
  float inv = 1.f/red[0];
  float oacc = 0.f;
  for (int j = w; j < 1025; j += 4)
    oacc += sc[j]*bf2f(qkv[base + (size_t)j*1536 + 1024 + lane]);
  opart[w][lane] = oacc; __syncthreads();
  if (t < 64){
    float v = (opart[0][t]+opart[1][t]+opart[2][t]+opart[3][t])*inv;
    ao[((size_t)(b*1025+1024))*512 + hh*64 + t] = f2bf(v);
  }
}

// ---------------- residual + LayerNorm (row=512), one wave per row ----------------
__global__ __launch_bounds__(256) void addln_k(float* __restrict__ h, const float* __restrict__ t1,
      const float* __restrict__ g, const float* __restrict__ be, u16* __restrict__ hb){
  int row = blockIdx.x*4 + (threadIdx.x>>6);
  int lane = threadIdx.x & 63;
  size_t base = (size_t)row*512;
  const float4 a0 = *(const float4*)&h[base + lane*4];
  const float4 a1 = *(const float4*)&h[base + 256 + lane*4];
  const float4 b0 = *(const float4*)&t1[base + lane*4];
  const float4 b1 = *(const float4*)&t1[base + 256 + lane*4];
  float v[8];
  v[0]=a0.x+b0.x; v[1]=a0.y+b0.y; v[2]=a0.z+b0.z; v[3]=a0.w+b0.w;
  v[4]=a1.x+b1.x; v[5]=a1.y+b1.y; v[6]=a1.z+b1.z; v[7]=a1.w+b1.w;
  float s=0.f, s2=0.f;
#pragma unroll
  for (int i=0;i<8;++i){ s += v[i]; s2 += v[i]*v[i]; }
#pragma unroll
  for (int o2=1;o2<64;o2<<=1){ s += __shfl_xor(s,o2); s2 += __shfl_xor(s2,o2); }
  float mean = s * (1.f/512.f);
  float var = s2 * (1.f/512.f) - mean*mean;
  float inv = rsqrtf(var + 1e-5f);
  const float4 g0 = *(const float4*)&g[lane*4];
  const float4 g1 = *(const float4*)&g[256 + lane*4];
  const float4 e0 = *(const float4*)&be[lane*4];
  const float4 e1 = *(const float4*)&be[256 + lane*4];
  float y[8];
  y[0]=(v[0]-mean)*inv*g0.x+e0.x; y[1]=(v[1]-mean)*inv*g0.y+e0.y;
  y[2]=(v[2]-mean)*inv*g0.z+e0.z; y[3]=(v[3]-mean)*inv*g0.w+e0.w;
  y[4]=(v[4]-mean)*inv*g1.x+e1.x; y[5]=(v[5]-mean)*inv*g1.y+e1.y;
  y[6]=(v[6]-mean)*inv*g1.z+e1.z; y[7]=(v[7]-mean)*inv*g1.w+e1.w;
  float4 o0 = {y[0],y[1],y[2],y[3]}, o1 = {y[4],y[5],y[6],y[7]};
  *(float4*)&h[base + lane*4] = o0;
  *(float4*)&h[base + 256 + lane*4] = o1;
  ushort4 u0, u1;
  u0.x=f2bf(y[0]); u0.y=f2bf(y[1]); u0.z=f2bf(y[2]); u0.w=f2bf(y[3]);
  u1.x=f2bf(y[4]); u1.y=f2bf(y[5]); u1.z=f2bf(y[6]); u1.w=f2bf(y[7]);
  *(ushort4*)&hb[base + lane*4] = u0;
  *(ushort4*)&hb[base + 256 + lane*4] = u1;
}

// ---------------- heads (f32, exact) ----------------
__global__ __launch_bounds__(256) void voice_k(const float* __restrict__ h, const float* __restrict__ W,
                                               const float* __restrict__ bias, float* __restrict__ out){
  int pair = blockIdx.x*4 + (threadIdx.x>>6);   // 0..2047 : b*128 + c
  int lane = threadIdx.x & 63;
  int b = pair >> 7, c = pair & 127;
  const float* hr = h + ((size_t)(b*1025 + 1024))*512;
  const float* wr = W + (size_t)c*512;
  float p = 0.f;
#pragma unroll
  for (int j=0;j<8;++j) p += hr[lane + 64*j]*wr[lane + 64*j];
#pragma unroll
  for (int o2=1;o2<64;o2<<=1) p += __shfl_xor(p,o2);
  if (lane == 0) out[b*128 + c] = p + bias[c];
}

__global__ __launch_bounds__(256) void phon_k(const float* __restrict__ h, const float* __restrict__ W,
                                              const float* __restrict__ bias, float* __restrict__ out){
  int row = blockIdx.x*4 + (threadIdx.x>>6);    // 0..16383 : b*1024 + s
  int lane = threadIdx.x & 63;
  int b = row >> 10, s = row & 1023;
  const float* hr = h + ((size_t)(b*1025 + s))*512;
  float hv[8];
#pragma unroll
  for (int j=0;j<8;++j) hv[j] = hr[lane + 64*j];
#pragma unroll
  for (int c=0;c<10;++c){
    float p = 0.f;
#pragma unroll
    for (int j=0;j<8;++j) p += hv[j]*W[c*512 + lane + 64*j];
#pragma unroll
    for (int o2=1;o2<64;o2<<=1) p += __shfl_xor(p,o2);
    if (lane == c) out[(size_t)row*10 + c] = p + bias[c];
  }
}

extern "C" void kernel_launch(void* const* d_in, const int* in_sizes, int n_in,
                              void* d_out, int out_size, void* d_ws, size_t ws_size,
                              hipStream_t stream) {
  const float* x      = (const float*)d_in[0];
  const float* cls    = (const float*)d_in[1];
  const float* preW   = (const float*)d_in[2];
  const float* preb   = (const float*)d_in[3];
  const float* ipW    = (const float*)d_in[4];
  const float* ipb    = (const float*)d_in[5];
  const float* oW     = (const float*)d_in[6];
  const float* ob     = (const float*)d_in[7];
  const float* f1W    = (const float*)d_in[8];
  const float* f1b    = (const float*)d_in[9];
  const float* f2W    = (const float*)d_in[10];
  const float* f2b    = (const float*)d_in[11];
  const float* ln1w   = (const float*)d_in[12];
  const float* ln1b   = (const float*)d_in[13];
  const float* ln2w   = (const float*)d_in[14];
  const float* ln2b   = (const float*)d_in[15];
  const float* voiceW = (const float*)d_in[16];
  const float* voiceb = (const float*)d_in[17];
  const float* phonW  = (const float*)d_in[18];
  const float* phonb  = (const float*)d_in[19];
  float* out = (float*)d_out;   // [voice 2048 | pitch 16384 | phoneme 163840]

  char* wsp = (char*)d_ws;
  size_t off = 0;
  auto alloc = [&](size_t nbytes)->void*{ void* p = wsp + off; off += (nbytes + 255) & ~(size_t)255; return p; };
  u16* preWb = (u16*)alloc((size_t)512*320*2);
  u16* ipWb  = (u16*)alloc((size_t)NLAYER*1536*512*2);
  u16* oWb   = (u16*)alloc((size_t)NLAYER*512*512*2);
  u16* f1Wb  = (u16*)alloc((size_t)NLAYER*2048*512*2);
  u16* f2Wb  = (u16*)alloc((size_t)NLAYER*512*2048*2);
  u16* feats = (u16*)alloc((size_t)MX*320*2);
  float* h   = (float*)alloc((size_t)MPAD*512*4);
  u16* hb    = (u16*)alloc((size_t)MPAD*512*2);
  u16* qkvb  = (u16*)alloc((size_t)MPAD*1536*2);
  u16* aob   = (u16*)alloc((size_t)MPAD*512*2);
  u16* ffb   = (u16*)alloc((size_t)MPAD*2048*2);
  float* t1  = (float*)alloc((size_t)MPAD*512*4);

  // weight converts (per-launch: ws is re-poisoned each call)
  { int n4 = NLAYER*1536*512/4; cvt_k<<<(n4+255)/256,256,0,stream>>>(ipW, ipWb, n4); }
  { int n4 = NLAYER*512*512/4;  cvt_k<<<(n4+255)/256,256,0,stream>>>(oW, oWb, n4); }
  { int n4 = NLAYER*2048*512/4; cvt_k<<<(n4+255)/256,256,0,stream>>>(f1W, f1Wb, n4); }
  { int n4 = NLAYER*512*2048/4; cvt_k<<<(n4+255)/256,256,0,stream>>>(f2W, f2Wb, n4); }
  cvt_pre_k<<<(512*320+255)/256,256,0,stream>>>(preW, preWb);

  // preproc + pre-projection + assemble h
  prep_k<<<MX,128,0,stream>>>(x, feats, out + 2048);
  gemm_k<64,64,false,false,true><<<(MX/128)*8,256,0,stream>>>(feats, preWb, preb, nullptr, t1, 512, 320, 8);
  assemble_k<<<(MPAD*512)/256,256,0,stream>>>(t1, cls, h, hb);

  for (int l = 0; l < NLAYER; ++l){
    gemm_k<128,64,false,true,false><<<(MPAD/128)*12,256,0,stream>>>(hb, ipWb + (size_t)l*1536*512, ipb + l*1536, qkvb, nullptr, 1536, 512, 12);
    attn_win_k<<<(BB*HH*1024)/4,256,0,stream>>>(qkvb, aob);
    attn_last_k<<<BB*HH,256,0,stream>>>(qkvb, aob);
    gemm_k<64,128,false,false,true><<<(MPAD/128)*8,256,0,stream>>>(aob, oWb + (size_t)l*512*512, ob + l*512, nullptr, t1, 512, 512, 8);
    addln_k<<<MPAD/4,256,0,stream>>>(h, t1, ln1w + l*512, ln1b + l*512, hb);
    gemm_k<128,64,true,true,false><<<(MPAD/128)*16,256,0,stream>>>(hb, f1Wb + (size_t)l*2048*512, f1b + l*2048, ffb, nullptr, 2048, 512, 16);
    gemm_k<64,128,false,false,true><<<(MPAD/128)*8,256,0,stream>>>(ffb, f2Wb + (size_t)l*512*2048, f2b + l*512, nullptr, t1, 512, 2048, 8);
    addln_k<<<MPAD/4,256,0,stream>>>(h, t1, ln2w + l*512, ln2b + l*512, hb);
  }

  voice_k<<<512,256,0,stream>>>(h, voiceW, voiceb, out);
  phon_k<<<4096,256,0,stream>>>(h, phonW, phonb, out + 2048 + 16384);
}

// Round 11
// 1995.498 us; speedup vs baseline: 1.4492x; 1.4492x over previous
//
#include <hip/hip_runtime.h>

typedef unsigned short u16;
typedef __bf16 bf16x8 __attribute__((ext_vector_type(8)));
typedef float f32x4 __attribute__((ext_vector_type(4)));

#define DEVINL __device__ __forceinline__

DEVINL float bf2f(u16 u){ union{unsigned u32; float f;} v; v.u32=(unsigned)u<<16; return v.f; }
DEVINL u16 f2bf(float f){ union{float f; unsigned u;} v; v.f=f; return (u16)((v.u + 0x7FFFu + ((v.u>>16)&1u))>>16); }

DEVINL void gload16(const u16* g, u16* l){
  __builtin_amdgcn_global_load_lds((const __attribute__((address_space(1))) void*)g,
                                   (__attribute__((address_space(3))) void*)l, 16, 0, 0);
}

// dims
#define BB 16
#define TT 1024
#define SS 1025
#define DD 512
#define HH 8
#define FFD 2048
#define NLAYER 6
#define MROWS (BB*SS)      // 16400
#define MPAD  16512        // 129*128
#define MX    (BB*TT)      // 16384
#define NCHUNK 17          // ceil(1025/64)

// ---------------- weight conversion ----------------
__global__ __launch_bounds__(256) void cvt_k(const float* __restrict__ in, u16* __restrict__ out, int n4){
  int i = blockIdx.x*256 + threadIdx.x;
  if (i < n4){
    const float4 v = ((const float4*)in)[i];
    ushort4 o; o.x=f2bf(v.x); o.y=f2bf(v.y); o.z=f2bf(v.z); o.w=f2bf(v.w);
    ((ushort4*)out)[i] = o;
  }
}

__global__ __launch_bounds__(256) void cvt_pre_k(const float* __restrict__ in, u16* __restrict__ out){
  int i = blockIdx.x*256 + threadIdx.x; // 512*320
  if (i < 512*320){
    int r = i / 320, c = i - r*320;
    out[i] = (c < 306) ? f2bf(in[r*306 + c]) : (u16)0;
  }
}

// ---------------- preproc: build feats (bf16, 16384 x 320), emit pitch ----------------
__global__ __launch_bounds__(128) void prep_k(const float* __restrict__ x, u16* __restrict__ feats, float* __restrict__ pitch_out){
  int row = blockIdx.x;            // 0..16383  (b*1024 + t)
  int t = row & 1023;
  const float* xr = x + (size_t)row*291;
  float pitch = xr[0];
  if (threadIdx.x == 0) pitch_out[row] = pitch;
  for (int c = threadIdx.x; c < 320; c += 128){
    float v;
    if (c < 290) v = xr[1+c];
    else if (c < 306){
      int i = (c < 298) ? (c-290) : (c-298);
      float base = (c < 298) ? pitch : (float)t;
      int fi = i & 3;
      float f = (fi==0)?1.f:(fi==1)?0.1f:(fi==2)?0.01f:0.001f;
      float a = base * f;
      v = (i < 4) ? sinf(a) : cosf(a);
    }
    else v = 0.f;
    feats[(size_t)row*320 + c] = f2bf(v);
  }
}

// ---------------- assemble h from pre-proj + cls, zero pad rows ----------------
__global__ __launch_bounds__(256) void assemble_k(const float* __restrict__ t1, const float* __restrict__ cls,
                                                  float* __restrict__ h, u16* __restrict__ hb){
  int idx = blockIdx.x*256 + threadIdx.x;
  if (idx >= MPAD*DD) return;
  int r = idx >> 9, d = idx & 511;
  float v = 0.f;
  if (r < MROWS){
    int b = r / 1025, s = r - b*1025;
    v = (s < 1024) ? t1[((size_t)b*1024 + s)*512 + d] : cls[d];
  }
  h[idx] = v; hb[idx] = f2bf(v);
}

// ---------------- GEMM: C[M,N] = A[M,K](bf16) * W[N,K]^T + bias ----------------
// BM=128; BN in {64,128}; BK in {64,128}. XCD-bijective block swizzle (T1).
// T2 swizzle via pre-swizzled global source + swizzled LDS read (LDS linear
// for global_load_lds). BK=128 halves barrier count for BN=64 kernels.
template<int BN, int BK, bool RELU, bool WBF, bool WF32>
__global__ __launch_bounds__(256)
void gemm_k(const u16* __restrict__ A, const u16* __restrict__ W,
            const float* __restrict__ bias, u16* __restrict__ obf,
            float* __restrict__ of32, int N, int K, int gy)
{
  __shared__ u16 As[128*BK];
  __shared__ u16 Ws[BN*BK];
  constexpr int NREP = BN/32;        // col fragments per wave (wave covers BN/2 cols)
  constexpr int KK = BK/32;          // K32 sub-steps per tile
  constexpr int GR = BK/8;           // 16B granules per row
  constexpr int AR = (128*BK)/2048;  // A staging rounds
  constexpr int WR = (BN*BK)/2048;   // W staging rounds
  const int tid = threadIdx.x;
  const int lane = tid & 63, wave = tid >> 6;
  const int wr = wave >> 1, wc = wave & 1;
  const int lr = lane & 15;
  const int x7 = lane & 7;           // == fragment_row & 7 for this lane
  const int gbase = lane >> 4;       // column granule base within K32 block

  // bijective 8-XCD swizzle (m204)
  const int nwg = gridDim.x;
  const int id = blockIdx.x;
  const int q = nwg >> 3, r8 = nwg & 7;
  const int xcd = id & 7, pos = id >> 3;
  const int wgid = (xcd < r8 ? xcd*(q+1) : r8*(q+1) + (xcd-r8)*q) + pos;
  const int bx = wgid / gy, by = wgid - bx*gy;
  const int m0 = bx * 128, n0 = by * BN;

  // swizzled column offsets (elems) for each K32 half
  int colsw[KK];
#pragma unroll
  for (int kk=0; kk<KK; ++kk){
    int gk = kk*4 + gbase;
    colsw[kk] = ((gk & ~7) | ((gk & 7) ^ x7)) * 8;
  }

  int aoff[4], boff[NREP];
#pragma unroll
  for (int i=0;i<4;++i) aoff[i] = (wr*64 + i*16 + lr)*BK;
#pragma unroll
  for (int i=0;i<NREP;++i) boff[i] = (wc*(BN/2) + i*16 + lr)*BK;

  f32x4 acc[4][NREP];
#pragma unroll
  for (int n=0;n<NREP;++n){
    float bv = bias[n0 + wc*(BN/2) + n*16 + lr];
#pragma unroll
    for (int m=0;m<4;++m) acc[m][n] = (f32x4){bv,bv,bv,bv};
  }

  for (int k0=0; k0<K; k0+=BK) {
#pragma unroll
    for (int r=0;r<AR;++r){
      int cb = r*256 + wave*64;
      int chunk = cb + lane;
      int row = chunk / GR, gp = chunk & (GR-1);
      int kc = ((gp & ~7) | ((gp & 7) ^ (row & 7))) * 8;   // pre-swizzled source
      gload16(A + (size_t)(m0+row)*K + k0 + kc, &As[cb*8]);
    }
#pragma unroll
    for (int r=0;r<WR;++r){
      int cb = r*256 + wave*64;
      int chunk = cb + lane;
      int row = chunk / GR, gp = chunk & (GR-1);
      int kc = ((gp & ~7) | ((gp & 7) ^ (row & 7))) * 8;
      gload16(W + (size_t)(n0+row)*K + k0 + kc, &Ws[cb*8]);
    }
    __syncthreads();
#pragma unroll
    for (int kk=0; kk<KK; ++kk){
      bf16x8 af[4], bfr[NREP];
#pragma unroll
      for (int m=0;m<4;++m) af[m] = *(const bf16x8*)&As[aoff[m] + colsw[kk]];
#pragma unroll
      for (int n=0;n<NREP;++n) bfr[n] = *(const bf16x8*)&Ws[boff[n] + colsw[kk]];
#pragma unroll
      for (int m=0;m<4;++m)
#pragma unroll
        for (int n=0;n<NREP;++n)
          acc[m][n] = __builtin_amdgcn_mfma_f32_16x16x32_bf16(af[m], bfr[n], acc[m][n], 0,0,0);
    }
    __syncthreads();
  }

  const int orow = m0 + wr*64 + (lane>>4)*4;
  const int ocol = n0 + wc*(BN/2) + lr;
#pragma unroll
  for (int m=0;m<4;++m)
#pragma unroll
    for (int n=0;n<NREP;++n){
#pragma unroll
      for (int j=0;j<4;++j){
        float v = acc[m][n][j];
        if (RELU) v = fmaxf(v, 0.f);
        size_t idx = (size_t)(orow + m*16 + j) * N + (ocol + n*16);
        if (WBF) obf[idx] = f2bf(v);
        if (WF32) of32[idx] = v;
      }
    }
}

// ---------------- windowed attention: one wave per (b,h,q), q in [0,1023] ----------------
__global__ __launch_bounds__(256) void attn_win_k(const u16* __restrict__ qkv, u16* __restrict__ ao){
  int wid = blockIdx.x*4 + (threadIdx.x>>6);
  int lane = threadIdx.x & 63;
  int q = wid & 1023, bh = wid >> 10;
  int hh = bh & 7, b = bh >> 3;
  float qv = bf2f(qkv[((size_t)(b*1025+q))*1536 + hh*64 + lane]);
  float sc[7];
#pragma unroll
  for (int jj=0;jj<7;++jj){
    int j = q - 3 + jj;
    int jc = min(max(j,0),1024);
    float kv = bf2f(qkv[((size_t)(b*1025+jc))*1536 + 512 + hh*64 + lane]);
    float p = qv * kv;
#pragma unroll
    for (int o2=1;o2<64;o2<<=1) p += __shfl_xor(p, o2);
    sc[jj] = (j>=0 && j<=1024) ? p*0.125f : -1e30f;
  }
  float m = sc[0];
#pragma unroll
  for (int jj=1;jj<7;++jj) m = fmaxf(m, sc[jj]);
  float l = 0.f, pj[7];
#pragma unroll
  for (int jj=0;jj<7;++jj){ pj[jj] = expf(sc[jj]-m); l += pj[jj]; }
  float o = 0.f;
#pragma unroll
  for (int jj=0;jj<7;++jj){
    int jc = min(max(q-3+jj,0),1024);
    float vv = bf2f(qkv[((size_t)(b*1025+jc))*1536 + 1024 + hh*64 + lane]);
    o += pj[jj]*vv;
  }
  ao[((size_t)(b*1025+q))*512 + hh*64 + lane] = f2bf(o / l);
}

// ---------------- last-row attention, pass 1: per-(b,h,chunk) flash partials ----
// 2176 waves (544 blocks x 4): wave = (bh, chunk of <=64 keys); lane = d.
__global__ __launch_bounds__(256) void attn_last1_k(const u16* __restrict__ qkv,
      float* __restrict__ pm, float* __restrict__ pl, float* __restrict__ po){
  int wid = blockIdx.x*4 + (threadIdx.x>>6);   // 0..2175
  int lane = threadIdx.x & 63;
  int bh = wid / NCHUNK, c = wid - bh*NCHUNK;
  int b = bh >> 3, hh = bh & 7;
  size_t base = (size_t)(b*1025)*1536 + hh*64;
  float qv = bf2f(qkv[base + (size_t)1024*1536 + lane]);
  int j0 = c*64, j1 = min(j0+64, 1025);
  float m = -1e30f, l = 0.f, o = 0.f;
  for (int j = j0; j < j1; ++j){
    float kv = bf2f(qkv[base + (size_t)j*1536 + 512 + lane]);
    float vv = bf2f(qkv[base + (size_t)j*1536 + 1024 + lane]);
    float p = qv * kv;
#pragma unroll
    for (int o2=1;o2<64;o2<<=1) p += __shfl_xor(p, o2);
    float s = p * 0.125f;
    float mn = fmaxf(m, s);
    float corr = expf(m - mn);
    float pe = expf(s - mn);
    l = l*corr + pe;
    o = o*corr + pe*vv;
    m = mn;
  }
  if (lane == 0){ pm[wid] = m; pl[wid] = l; }
  po[(size_t)wid*64 + lane] = o;
}

// ---------------- last-row attention, pass 2: merge 17 partials per (b,h) ----
__global__ __launch_bounds__(256) void attn_last2_k(const float* __restrict__ pm,
      const float* __restrict__ pl, const float* __restrict__ po, u16* __restrict__ ao){
  int bh = blockIdx.x*4 + (threadIdx.x>>6);    // 0..127
  int lane = threadIdx.x & 63;
  int b = bh >> 3, hh = bh & 7;
  float M = -1e30f;
#pragma unroll
  for (int c=0;c<NCHUNK;++c) M = fmaxf(M, pm[bh*NCHUNK+c]);
  float L = 0.f, o = 0.f;
#pragma unroll
  for (int c=0;c<NCHUNK;++c){
    float w = expf(pm[bh*NCHUNK+c] - M);
    L += pl[bh*NCHUNK+c]*w;
    o += po[(size_t)(bh*NCHUNK+c)*64 + lane]*w;
  }
  ao[((size_t)(b*1025+1024))*512 + hh*64 + lane] = f2bf(o / L);
}

// ---------------- residual + LayerNorm (row=512), one wave per row ----------------
__global__ __launch_bounds__(256) void addln_k(float* __restrict__ h, const float* __restrict__ t1,
      const float* __restrict__ g, const float* __restrict__ be, u16* __restrict__ hb){
  int row = blockIdx.x*4 + (threadIdx.x>>6);
  int lane = threadIdx.x & 63;
  size_t base = (size_t)row*512;
  const float4 a0 = *(const float4*)&h[base + lane*4];
  const float4 a1 = *(const float4*)&h[base + 256 + lane*4];
  const float4 b0 = *(const float4*)&t1[base + lane*4];
  const float4 b1 = *(const float4*)&t1[base + 256 + lane*4];
  float v[8];
  v[0]=a0.x+b0.x; v[1]=a0.y+b0.y; v[2]=a0.z+b0.z; v[3]=a0.w+b0.w;
  v[4]=a1.x+b1.x; v[5]=a1.y+b1.y; v[6]=a1.z+b1.z; v[7]=a1.w+b1.w;
  float s=0.f, s2=0.f;
#pragma unroll
  for (int i=0;i<8;++i){ s += v[i]; s2 += v[i]*v[i]; }
#pragma unroll
  for (int o2=1;o2<64;o2<<=1){ s += __shfl_xor(s,o2); s2 += __shfl_xor(s2,o2); }
  float mean = s * (1.f/512.f);
  float var = s2 * (1.f/512.f) - mean*mean;
  float inv = rsqrtf(var + 1e-5f);
  const float4 g0 = *(const float4*)&g[lane*4];
  const float4 g1 = *(const float4*)&g[256 + lane*4];
  const float4 e0 = *(const float4*)&be[lane*4];
  const float4 e1 = *(const float4*)&be[256 + lane*4];
  float y[8];
  y[0]=(v[0]-mean)*inv*g0.x+e0.x; y[1]=(v[1]-mean)*inv*g0.y+e0.y;
  y[2]=(v[2]-mean)*inv*g0.z+e0.z; y[3]=(v[3]-mean)*inv*g0.w+e0.w;
  y[4]=(v[4]-mean)*inv*g1.x+e1.x; y[5]=(v[5]-mean)*inv*g1.y+e1.y;
  y[6]=(v[6]-mean)*inv*g1.z+e1.z; y[7]=(v[7]-mean)*inv*g1.w+e1.w;
  float4 o0 = {y[0],y[1],y[2],y[3]}, o1 = {y[4],y[5],y[6],y[7]};
  *(float4*)&h[base + lane*4] = o0;
  *(float4*)&h[base + 256 + lane*4] = o1;
  ushort4 u0, u1;
  u0.x=f2bf(y[0]); u0.y=f2bf(y[1]); u0.z=f2bf(y[2]); u0.w=f2bf(y[3]);
  u1.x=f2bf(y[4]); u1.y=f2bf(y[5]); u1.z=f2bf(y[6]); u1.w=f2bf(y[7]);
  *(ushort4*)&hb[base + lane*4] = u0;
  *(ushort4*)&hb[base + 256 + lane*4] = u1;
}

// ---------------- heads (f32, exact) ----------------
__global__ __launch_bounds__(256) void voice_k(const float* __restrict__ h, const float* __restrict__ W,
                                               const float* __restrict__ bias, float* __restrict__ out){
  int pair = blockIdx.x*4 + (threadIdx.x>>6);   // 0..2047 : b*128 + c
  int lane = threadIdx.x & 63;
  int b = pair >> 7, c = pair & 127;
  const float* hr = h + ((size_t)(b*1025 + 1024))*512;
  const float* wr = W + (size_t)c*512;
  float p = 0.f;
#pragma unroll
  for (int j=0;j<8;++j) p += hr[lane + 64*j]*wr[lane + 64*j];
#pragma unroll
  for (int o2=1;o2<64;o2<<=1) p += __shfl_xor(p,o2);
  if (lane == 0) out[b*128 + c] = p + bias[c];
}

__global__ __launch_bounds__(256) void phon_k(const float* __restrict__ h, const float* __restrict__ W,
                                              const float* __restrict__ bias, float* __restrict__ out){
  int row = blockIdx.x*4 + (threadIdx.x>>6);    // 0..16383 : b*1024 + s
  int lane = threadIdx.x & 63;
  int b = row >> 10, s = row & 1023;
  const float* hr = h + ((size_t)(b*1025 + s))*512;
  float hv[8];
#pragma unroll
  for (int j=0;j<8;++j) hv[j] = hr[lane + 64*j];
#pragma unroll
  for (int c=0;c<10;++c){
    float p = 0.f;
#pragma unroll
    for (int j=0;j<8;++j) p += hv[j]*W[c*512 + lane + 64*j];
#pragma unroll
    for (int o2=1;o2<64;o2<<=1) p += __shfl_xor(p,o2);
    if (lane == c) out[(size_t)row*10 + c] = p + bias[c];
  }
}

extern "C" void kernel_launch(void* const* d_in, const int* in_sizes, int n_in,
                              void* d_out, int out_size, void* d_ws, size_t ws_size,
                              hipStream_t stream) {
  const float* x      = (const float*)d_in[0];
  const float* cls    = (const float*)d_in[1];
  const float* preW   = (const float*)d_in[2];
  const float* preb   = (const float*)d_in[3];
  const float* ipW    = (const float*)d_in[4];
  const float* ipb    = (const float*)d_in[5];
  const float* oW     = (const float*)d_in[6];
  const float* ob     = (const float*)d_in[7];
  const float* f1W    = (const float*)d_in[8];
  const float* f1b    = (const float*)d_in[9];
  const float* f2W    = (const float*)d_in[10];
  const float* f2b    = (const float*)d_in[11];
  const float* ln1w   = (const float*)d_in[12];
  const float* ln1b   = (const float*)d_in[13];
  const float* ln2w   = (const float*)d_in[14];
  const float* ln2b   = (const float*)d_in[15];
  const float* voiceW = (const float*)d_in[16];
  const float* voiceb = (const float*)d_in[17];
  const float* phonW  = (const float*)d_in[18];
  const float* phonb  = (const float*)d_in[19];
  float* out = (float*)d_out;   // [voice 2048 | pitch 16384 | phoneme 163840]

  char* wsp = (char*)d_ws;
  size_t off = 0;
  auto alloc = [&](size_t nbytes)->void*{ void* p = wsp + off; off += (nbytes + 255) & ~(size_t)255; return p; };
  u16* preWb = (u16*)alloc((size_t)512*320*2);
  u16* ipWb  = (u16*)alloc((size_t)NLAYER*1536*512*2);
  u16* oWb   = (u16*)alloc((size_t)NLAYER*512*512*2);
  u16* f1Wb  = (u16*)alloc((size_t)NLAYER*2048*512*2);
  u16* f2Wb  = (u16*)alloc((size_t)NLAYER*512*2048*2);
  u16* feats = (u16*)alloc((size_t)MX*320*2);
  float* h   = (float*)alloc((size_t)MPAD*512*4);
  u16* hb    = (u16*)alloc((size_t)MPAD*512*2);
  u16* qkvb  = (u16*)alloc((size_t)MPAD*1536*2);
  u16* aob   = (u16*)alloc((size_t)MPAD*512*2);
  u16* ffb   = (u16*)alloc((size_t)MPAD*2048*2);
  float* t1  = (float*)alloc((size_t)MPAD*512*4);
  // pm/pl/po ALIAS the feats buffer (feats is dead after the pre-GEMM;
  // adding fresh allocations overflowed the 256 MiB workspace -> round-10 abort).
  float* pm  = (float*)feats;                       // 128*17*4      = 8.7 KB
  float* pl  = pm + (size_t)BB*HH*NCHUNK;           // 8.7 KB
  float* po  = pl + (size_t)BB*HH*NCHUNK;           // 128*17*64*4   = 557 KB  (total 574 KB << 10.5 MB)

  // weight converts (per-launch: ws is re-poisoned each call)
  { int n4 = NLAYER*1536*512/4; cvt_k<<<(n4+255)/256,256,0,stream>>>(ipW, ipWb, n4); }
  { int n4 = NLAYER*512*512/4;  cvt_k<<<(n4+255)/256,256,0,stream>>>(oW, oWb, n4); }
  { int n4 = NLAYER*2048*512/4; cvt_k<<<(n4+255)/256,256,0,stream>>>(f1W, f1Wb, n4); }
  { int n4 = NLAYER*512*2048/4; cvt_k<<<(n4+255)/256,256,0,stream>>>(f2W, f2Wb, n4); }
  cvt_pre_k<<<(512*320+255)/256,256,0,stream>>>(preW, preWb);

  // preproc + pre-projection + assemble h
  prep_k<<<MX,128,0,stream>>>(x, feats, out + 2048);
  gemm_k<64,64,false,false,true><<<(MX/128)*8,256,0,stream>>>(feats, preWb, preb, nullptr, t1, 512, 320, 8);
  assemble_k<<<(MPAD*512)/256,256,0,stream>>>(t1, cls, h, hb);

  for (int l = 0; l < NLAYER; ++l){
    gemm_k<128,64,false,true,false><<<(MPAD/128)*12,256,0,stream>>>(hb, ipWb + (size_t)l*1536*512, ipb + l*1536, qkvb, nullptr, 1536, 512, 12);
    attn_win_k<<<(BB*HH*1024)/4,256,0,stream>>>(qkvb, aob);
    attn_last1_k<<<(BB*HH*NCHUNK)/4,256,0,stream>>>(qkvb, pm, pl, po);
    attn_last2_k<<<(BB*HH)/4,256,0,stream>>>(pm, pl, po, aob);
    gemm_k<64,128,false,false,true><<<(MPAD/128)*8,256,0,stream>>>(aob, oWb + (size_t)l*512*512, ob + l*512, nullptr, t1, 512, 512, 8);
    addln_k<<<MPAD/4,256,0,stream>>>(h, t1, ln1w + l*512, ln1b + l*512, hb);
    gemm_k<128,64,true,true,false><<<(MPAD/128)*16,256,0,stream>>>(hb, f1Wb + (size_t)l*2048*512, f1b + l*2048, ffb, nullptr, 2048, 512, 16);
    gemm_k<64,128,false,false,true><<<(MPAD/128)*8,256,0,stream>>>(ffb, f2Wb + (size_t)l*512*2048, f2b + l*512, nullptr, t1, 512, 2048, 8);
    addln_k<<<MPAD/4,256,0,stream>>>(h, t1, ln2w + l*512, ln2b + l*512, hb);
  }

  voice_k<<<512,256,0,stream>>>(h, voiceW, voiceb, out);
  phon_k<<<4096,256,0,stream>>>(h, phonW, phonb, out + 2048 + 16384);
}

// Round 12
// 1752.393 us; speedup vs baseline: 1.6502x; 1.1387x over previous
//
#include <hip/hip_runtime.h>

typedef unsigned short u16;
typedef __bf16 bf16x8 __attribute__((ext_vector_type(8)));
typedef float f32x4 __attribute__((ext_vector_type(4)));

#define DEVINL __device__ __forceinline__

DEVINL float bf2f(u16 u){ union{unsigned u32; float f;} v; v.u32=(unsigned)u<<16; return v.f; }
DEVINL u16 f2bf(float f){ union{float f; unsigned u;} v; v.f=f; return (u16)((v.u + 0x7FFFu + ((v.u>>16)&1u))>>16); }

DEVINL void gload16(const u16* g, u16* l){
  __builtin_amdgcn_global_load_lds((const __attribute__((address_space(1))) void*)g,
                                   (__attribute__((address_space(3))) void*)l, 16, 0, 0);
}

// dims
#define BB 16
#define TT 1024
#define SS 1025
#define DD 512
#define HH 8
#define FFD 2048
#define NLAYER 6
#define MROWS (BB*SS)      // 16400
#define MPAD  16512        // 129*128
#define MX    (BB*TT)      // 16384
#define NCHUNK 17          // ceil(1025/64)

// ---------------- weight conversion ----------------
__global__ __launch_bounds__(256) void cvt_k(const float* __restrict__ in, u16* __restrict__ out, int n4){
  int i = blockIdx.x*256 + threadIdx.x;
  if (i < n4){
    const float4 v = ((const float4*)in)[i];
    ushort4 o; o.x=f2bf(v.x); o.y=f2bf(v.y); o.z=f2bf(v.z); o.w=f2bf(v.w);
    ((ushort4*)out)[i] = o;
  }
}

__global__ __launch_bounds__(256) void cvt_pre_k(const float* __restrict__ in, u16* __restrict__ out){
  int i = blockIdx.x*256 + threadIdx.x; // 512*320
  if (i < 512*320){
    int r = i / 320, c = i - r*320;
    out[i] = (c < 306) ? f2bf(in[r*306 + c]) : (u16)0;
  }
}

// ---------------- preproc: build feats (bf16, 16384 x 320), emit pitch ----------------
__global__ __launch_bounds__(128) void prep_k(const float* __restrict__ x, u16* __restrict__ feats, float* __restrict__ pitch_out){
  int row = blockIdx.x;            // 0..16383  (b*1024 + t)
  int t = row & 1023;
  const float* xr = x + (size_t)row*291;
  float pitch = xr[0];
  if (threadIdx.x == 0) pitch_out[row] = pitch;
  for (int c = threadIdx.x; c < 320; c += 128){
    float v;
    if (c < 290) v = xr[1+c];
    else if (c < 306){
      int i = (c < 298) ? (c-290) : (c-298);
      float base = (c < 298) ? pitch : (float)t;
      int fi = i & 3;
      float f = (fi==0)?1.f:(fi==1)?0.1f:(fi==2)?0.01f:0.001f;
      float a = base * f;
      v = (i < 4) ? sinf(a) : cosf(a);
    }
    else v = 0.f;
    feats[(size_t)row*320 + c] = f2bf(v);
  }
}

// ---------------- assemble h from pre-proj + cls, zero pad rows ----------------
__global__ __launch_bounds__(256) void assemble_k(const float* __restrict__ t1, const float* __restrict__ cls,
                                                  float* __restrict__ h, u16* __restrict__ hb){
  int idx = blockIdx.x*256 + threadIdx.x;
  if (idx >= MPAD*DD) return;
  int r = idx >> 9, d = idx & 511;
  float v = 0.f;
  if (r < MROWS){
    int b = r / 1025, s = r - b*1025;
    v = (s < 1024) ? t1[((size_t)b*1024 + s)*512 + d] : cls[d];
  }
  h[idx] = v; hb[idx] = f2bf(v);
}

// ---------------- GEMM: C[M,N] = A[M,K](bf16) * W[N,K]^T + bias ----------------
// BM=128; BN in {64,128}; BK in {64,128}. XCD-bijective block swizzle (T1).
// T2 swizzle via pre-swizzled global source + swizzled LDS read (LDS linear
// for global_load_lds). BK=128 halves barrier count for BN=64 kernels.
template<int BN, int BK, bool RELU, bool WBF, bool WF32>
__global__ __launch_bounds__(256)
void gemm_k(const u16* __restrict__ A, const u16* __restrict__ W,
            const float* __restrict__ bias, u16* __restrict__ obf,
            float* __restrict__ of32, int N, int K, int gy)
{
  __shared__ u16 As[128*BK];
  __shared__ u16 Ws[BN*BK];
  constexpr int NREP = BN/32;        // col fragments per wave (wave covers BN/2 cols)
  constexpr int KK = BK/32;          // K32 sub-steps per tile
  constexpr int GR = BK/8;           // 16B granules per row
  constexpr int AR = (128*BK)/2048;  // A staging rounds
  constexpr int WR = (BN*BK)/2048;   // W staging rounds
  const int tid = threadIdx.x;
  const int lane = tid & 63, wave = tid >> 6;
  const int wr = wave >> 1, wc = wave & 1;
  const int lr = lane & 15;
  const int x7 = lane & 7;           // == fragment_row & 7 for this lane
  const int gbase = lane >> 4;       // column granule base within K32 block

  // bijective 8-XCD swizzle (m204)
  const int nwg = gridDim.x;
  const int id = blockIdx.x;
  const int q = nwg >> 3, r8 = nwg & 7;
  const int xcd = id & 7, pos = id >> 3;
  const int wgid = (xcd < r8 ? xcd*(q+1) : r8*(q+1) + (xcd-r8)*q) + pos;
  const int bx = wgid / gy, by = wgid - bx*gy;
  const int m0 = bx * 128, n0 = by * BN;

  // swizzled column offsets (elems) for each K32 half
  int colsw[KK];
#pragma unroll
  for (int kk=0; kk<KK; ++kk){
    int gk = kk*4 + gbase;
    colsw[kk] = ((gk & ~7) | ((gk & 7) ^ x7)) * 8;
  }

  int aoff[4], boff[NREP];
#pragma unroll
  for (int i=0;i<4;++i) aoff[i] = (wr*64 + i*16 + lr)*BK;
#pragma unroll
  for (int i=0;i<NREP;++i) boff[i] = (wc*(BN/2) + i*16 + lr)*BK;

  f32x4 acc[4][NREP];
#pragma unroll
  for (int n=0;n<NREP;++n){
    float bv = bias[n0 + wc*(BN/2) + n*16 + lr];
#pragma unroll
    for (int m=0;m<4;++m) acc[m][n] = (f32x4){bv,bv,bv,bv};
  }

  for (int k0=0; k0<K; k0+=BK) {
#pragma unroll
    for (int r=0;r<AR;++r){
      int cb = r*256 + wave*64;
      int chunk = cb + lane;
      int row = chunk / GR, gp = chunk & (GR-1);
      int kc = ((gp & ~7) | ((gp & 7) ^ (row & 7))) * 8;   // pre-swizzled source
      gload16(A + (size_t)(m0+row)*K + k0 + kc, &As[cb*8]);
    }
#pragma unroll
    for (int r=0;r<WR;++r){
      int cb = r*256 + wave*64;
      int chunk = cb + lane;
      int row = chunk / GR, gp = chunk & (GR-1);
      int kc = ((gp & ~7) | ((gp & 7) ^ (row & 7))) * 8;
      gload16(W + (size_t)(n0+row)*K + k0 + kc, &Ws[cb*8]);
    }
    __syncthreads();
#pragma unroll
    for (int kk=0; kk<KK; ++kk){
      bf16x8 af[4], bfr[NREP];
#pragma unroll
      for (int m=0;m<4;++m) af[m] = *(const bf16x8*)&As[aoff[m] + colsw[kk]];
#pragma unroll
      for (int n=0;n<NREP;++n) bfr[n] = *(const bf16x8*)&Ws[boff[n] + colsw[kk]];
#pragma unroll
      for (int m=0;m<4;++m)
#pragma unroll
        for (int n=0;n<NREP;++n)
          acc[m][n] = __builtin_amdgcn_mfma_f32_16x16x32_bf16(af[m], bfr[n], acc[m][n], 0,0,0);
    }
    __syncthreads();
  }

  const int orow = m0 + wr*64 + (lane>>4)*4;
  const int ocol = n0 + wc*(BN/2) + lr;
#pragma unroll
  for (int m=0;m<4;++m)
#pragma unroll
    for (int n=0;n<NREP;++n){
#pragma unroll
      for (int j=0;j<4;++j){
        float v = acc[m][n][j];
        if (RELU) v = fmaxf(v, 0.f);
        size_t idx = (size_t)(orow + m*16 + j) * N + (ocol + n*16);
        if (WBF) obf[idx] = f2bf(v);
        if (WF32) of32[idx] = v;
      }
    }
}

// ---------------- windowed attention: 8 q per wave, 8 lanes per q ----------------
// lane = g*8+e: group g handles q = qb*8+g, elem octet e covers d = e*8..e*8+7.
// 16B loads; 8-lane group reduce = 3 shfl levels (vs 64-lane = 6).
__global__ __launch_bounds__(256) void attn_win_k(const u16* __restrict__ qkv, u16* __restrict__ ao){
  int wid = blockIdx.x*4 + (threadIdx.x>>6);   // 0..16383
  int lane = threadIdx.x & 63;
  int g = lane >> 3, e = lane & 7;
  int bh = wid >> 7, qb = wid & 127;
  int b = bh >> 3, hh = bh & 7;
  int q = qb*8 + g;
  const u16* basep = qkv + (size_t)(b*1025)*1536 + hh*64 + e*8;
  bf16x8 qv8 = *(const bf16x8*)(basep + (size_t)q*1536);
  float qf[8];
#pragma unroll
  for (int i=0;i<8;++i) qf[i] = (float)qv8[i];
  float sc[7];
#pragma unroll
  for (int jj=0;jj<7;++jj){
    int j = q - 3 + jj;
    int jc = min(max(j,0),1024);
    bf16x8 kv8 = *(const bf16x8*)(basep + (size_t)jc*1536 + 512);
    float p = 0.f;
#pragma unroll
    for (int i=0;i<8;++i) p += qf[i]*(float)kv8[i];
    p += __shfl_xor(p,1); p += __shfl_xor(p,2); p += __shfl_xor(p,4);
    sc[jj] = (j>=0 && j<=1024) ? p*0.125f : -1e30f;
  }
  float m = sc[0];
#pragma unroll
  for (int jj=1;jj<7;++jj) m = fmaxf(m, sc[jj]);
  float l = 0.f, pj[7];
#pragma unroll
  for (int jj=0;jj<7;++jj){ pj[jj] = expf(sc[jj]-m); l += pj[jj]; }
  float of[8];
#pragma unroll
  for (int i=0;i<8;++i) of[i] = 0.f;
#pragma unroll
  for (int jj=0;jj<7;++jj){
    int jc = min(max(q-3+jj,0),1024);
    bf16x8 vv8 = *(const bf16x8*)(basep + (size_t)jc*1536 + 1024);
#pragma unroll
    for (int i=0;i<8;++i) of[i] += pj[jj]*(float)vv8[i];
  }
  float inv = 1.f/l;
  uint4 w;
  w.x = (unsigned)f2bf(of[0]*inv) | ((unsigned)f2bf(of[1]*inv)<<16);
  w.y = (unsigned)f2bf(of[2]*inv) | ((unsigned)f2bf(of[3]*inv)<<16);
  w.z = (unsigned)f2bf(of[4]*inv) | ((unsigned)f2bf(of[5]*inv)<<16);
  w.w = (unsigned)f2bf(of[6]*inv) | ((unsigned)f2bf(of[7]*inv)<<16);
  *(uint4*)&ao[((size_t)(b*1025+q))*512 + hh*64 + e*8] = w;
}

// ---------------- last-row attention, pass 1: per-(b,h,chunk) flash partials ----
// 2176 waves (544 blocks x 4): wave = (bh, chunk of <=64 keys); lane = d.
__global__ __launch_bounds__(256) void attn_last1_k(const u16* __restrict__ qkv,
      float* __restrict__ pm, float* __restrict__ pl, float* __restrict__ po){
  int wid = blockIdx.x*4 + (threadIdx.x>>6);   // 0..2175
  int lane = threadIdx.x & 63;
  int bh = wid / NCHUNK, c = wid - bh*NCHUNK;
  int b = bh >> 3, hh = bh & 7;
  size_t base = (size_t)(b*1025)*1536 + hh*64;
  float qv = bf2f(qkv[base + (size_t)1024*1536 + lane]);
  int j0 = c*64, j1 = min(j0+64, 1025);
  float m = -1e30f, l = 0.f, o = 0.f;
  for (int j = j0; j < j1; ++j){
    float kv = bf2f(qkv[base + (size_t)j*1536 + 512 + lane]);
    float vv = bf2f(qkv[base + (size_t)j*1536 + 1024 + lane]);
    float p = qv * kv;
#pragma unroll
    for (int o2=1;o2<64;o2<<=1) p += __shfl_xor(p, o2);
    float s = p * 0.125f;
    float mn = fmaxf(m, s);
    float corr = expf(m - mn);
    float pe = expf(s - mn);
    l = l*corr + pe;
    o = o*corr + pe*vv;
    m = mn;
  }
  if (lane == 0){ pm[wid] = m; pl[wid] = l; }
  po[(size_t)wid*64 + lane] = o;
}

// ---------------- last-row attention, pass 2: merge 17 partials per (b,h) ----
__global__ __launch_bounds__(256) void attn_last2_k(const float* __restrict__ pm,
      const float* __restrict__ pl, const float* __restrict__ po, u16* __restrict__ ao){
  int bh = blockIdx.x*4 + (threadIdx.x>>6);    // 0..127
  int lane = threadIdx.x & 63;
  int b = bh >> 3, hh = bh & 7;
  float M = -1e30f;
#pragma unroll
  for (int c=0;c<NCHUNK;++c) M = fmaxf(M, pm[bh*NCHUNK+c]);
  float L = 0.f, o = 0.f;
#pragma unroll
  for (int c=0;c<NCHUNK;++c){
    float w = expf(pm[bh*NCHUNK+c] - M);
    L += pl[bh*NCHUNK+c]*w;
    o += po[(size_t)(bh*NCHUNK+c)*64 + lane]*w;
  }
  ao[((size_t)(b*1025+1024))*512 + hh*64 + lane] = f2bf(o / L);
}

// ---------------- residual + LayerNorm (row=512), one wave per row ----------------
__global__ __launch_bounds__(256) void addln_k(float* __restrict__ h, const float* __restrict__ t1,
      const float* __restrict__ g, const float* __restrict__ be, u16* __restrict__ hb){
  int row = blockIdx.x*4 + (threadIdx.x>>6);
  int lane = threadIdx.x & 63;
  size_t base = (size_t)row*512;
  const float4 a0 = *(const float4*)&h[base + lane*4];
  const float4 a1 = *(const float4*)&h[base + 256 + lane*4];
  const float4 b0 = *(const float4*)&t1[base + lane*4];
  const float4 b1 = *(const float4*)&t1[base + 256 + lane*4];
  float v[8];
  v[0]=a0.x+b0.x; v[1]=a0.y+b0.y; v[2]=a0.z+b0.z; v[3]=a0.w+b0.w;
  v[4]=a1.x+b1.x; v[5]=a1.y+b1.y; v[6]=a1.z+b1.z; v[7]=a1.w+b1.w;
  float s=0.f, s2=0.f;
#pragma unroll
  for (int i=0;i<8;++i){ s += v[i]; s2 += v[i]*v[i]; }
#pragma unroll
  for (int o2=1;o2<64;o2<<=1){ s += __shfl_xor(s,o2); s2 += __shfl_xor(s2,o2); }
  float mean = s * (1.f/512.f);
  float var = s2 * (1.f/512.f) - mean*mean;
  float inv = rsqrtf(var + 1e-5f);
  const float4 g0 = *(const float4*)&g[lane*4];
  const float4 g1 = *(const float4*)&g[256 + lane*4];
  const float4 e0 = *(const float4*)&be[lane*4];
  const float4 e1 = *(const float4*)&be[256 + lane*4];
  float y[8];
  y[0]=(v[0]-mean)*inv*g0.x+e0.x; y[1]=(v[1]-mean)*inv*g0.y+e0.y;
  y[2]=(v[2]-mean)*inv*g0.z+e0.z; y[3]=(v[3]-mean)*inv*g0.w+e0.w;
  y[4]=(v[4]-mean)*inv*g1.x+e1.x; y[5]=(v[5]-mean)*inv*g1.y+e1.y;
  y[6]=(v[6]-mean)*inv*g1.z+e1.z; y[7]=(v[7]-mean)*inv*g1.w+e1.w;
  float4 o0 = {y[0],y[1],y[2],y[3]}, o1 = {y[4],y[5],y[6],y[7]};
  *(float4*)&h[base + lane*4] = o0;
  *(float4*)&h[base + 256 + lane*4] = o1;
  ushort4 u0, u1;
  u0.x=f2bf(y[0]); u0.y=f2bf(y[1]); u0.z=f2bf(y[2]); u0.w=f2bf(y[3]);
  u1.x=f2bf(y[4]); u1.y=f2bf(y[5]); u1.z=f2bf(y[6]); u1.w=f2bf(y[7]);
  *(ushort4*)&hb[base + lane*4] = u0;
  *(ushort4*)&hb[base + 256 + lane*4] = u1;
}

// ---------------- heads (f32, exact) ----------------
__global__ __launch_bounds__(256) void voice_k(const float* __restrict__ h, const float* __restrict__ W,
                                               const float* __restrict__ bias, float* __restrict__ out){
  int pair = blockIdx.x*4 + (threadIdx.x>>6);   // 0..2047 : b*128 + c
  int lane = threadIdx.x & 63;
  int b = pair >> 7, c = pair & 127;
  const float* hr = h + ((size_t)(b*1025 + 1024))*512;
  const float* wr = W + (size_t)c*512;
  float p = 0.f;
#pragma unroll
  for (int j=0;j<8;++j) p += hr[lane + 64*j]*wr[lane + 64*j];
#pragma unroll
  for (int o2=1;o2<64;o2<<=1) p += __shfl_xor(p,o2);
  if (lane == 0) out[b*128 + c] = p + bias[c];
}

__global__ __launch_bounds__(256) void phon_k(const float* __restrict__ h, const float* __restrict__ W,
                                              const float* __restrict__ bias, float* __restrict__ out){
  int row = blockIdx.x*4 + (threadIdx.x>>6);    // 0..16383 : b*1024 + s
  int lane = threadIdx.x & 63;
  int b = row >> 10, s = row & 1023;
  const float* hr = h + ((size_t)(b*1025 + s))*512;
  float hv[8];
#pragma unroll
  for (int j=0;j<8;++j) hv[j] = hr[lane + 64*j];
#pragma unroll
  for (int c=0;c<10;++c){
    float p = 0.f;
#pragma unroll
    for (int j=0;j<8;++j) p += hv[j]*W[c*512 + lane + 64*j];
#pragma unroll
    for (int o2=1;o2<64;o2<<=1) p += __shfl_xor(p,o2);
    if (lane == c) out[(size_t)row*10 + c] = p + bias[c];
  }
}

extern "C" void kernel_launch(void* const* d_in, const int* in_sizes, int n_in,
                              void* d_out, int out_size, void* d_ws, size_t ws_size,
                              hipStream_t stream) {
  const float* x      = (const float*)d_in[0];
  const float* cls    = (const float*)d_in[1];
  const float* preW   = (const float*)d_in[2];
  const float* preb   = (const float*)d_in[3];
  const float* ipW    = (const float*)d_in[4];
  const float* ipb    = (const float*)d_in[5];
  const float* oW     = (const float*)d_in[6];
  const float* ob     = (const float*)d_in[7];
  const float* f1W    = (const float*)d_in[8];
  const float* f1b    = (const float*)d_in[9];
  const float* f2W    = (const float*)d_in[10];
  const float* f2b    = (const float*)d_in[11];
  const float* ln1w   = (const float*)d_in[12];
  const float* ln1b   = (const float*)d_in[13];
  const float* ln2w   = (const float*)d_in[14];
  const float* ln2b   = (const float*)d_in[15];
  const float* voiceW = (const float*)d_in[16];
  const float* voiceb = (const float*)d_in[17];
  const float* phonW  = (const float*)d_in[18];
  const float* phonb  = (const float*)d_in[19];
  float* out = (float*)d_out;   // [voice 2048 | pitch 16384 | phoneme 163840]

  char* wsp = (char*)d_ws;
  size_t off = 0;
  auto alloc = [&](size_t nbytes)->void*{ void* p = wsp + off; off += (nbytes + 255) & ~(size_t)255; return p; };
  u16* preWb = (u16*)alloc((size_t)512*320*2);
  u16* ipWb  = (u16*)alloc((size_t)NLAYER*1536*512*2);
  u16* oWb   = (u16*)alloc((size_t)NLAYER*512*512*2);
  u16* f1Wb  = (u16*)alloc((size_t)NLAYER*2048*512*2);
  u16* f2Wb  = (u16*)alloc((size_t)NLAYER*512*2048*2);
  u16* feats = (u16*)alloc((size_t)MX*320*2);
  float* h   = (float*)alloc((size_t)MPAD*512*4);
  u16* hb    = (u16*)alloc((size_t)MPAD*512*2);
  u16* qkvb  = (u16*)alloc((size_t)MPAD*1536*2);
  u16* aob   = (u16*)alloc((size_t)MPAD*512*2);
  u16* ffb   = (u16*)alloc((size_t)MPAD*2048*2);
  float* t1  = (float*)alloc((size_t)MPAD*512*4);
  // pm/pl/po ALIAS the feats buffer (feats is dead after the pre-GEMM;
  // adding fresh allocations overflowed the 256 MiB workspace -> round-10 abort).
  float* pm  = (float*)feats;                       // 128*17*4      = 8.7 KB
  float* pl  = pm + (size_t)BB*HH*NCHUNK;           // 8.7 KB
  float* po  = pl + (size_t)BB*HH*NCHUNK;           // 128*17*64*4   = 557 KB  (total 574 KB << 10.5 MB)

  // weight converts (per-launch: ws is re-poisoned each call)
  { int n4 = NLAYER*1536*512/4; cvt_k<<<(n4+255)/256,256,0,stream>>>(ipW, ipWb, n4); }
  { int n4 = NLAYER*512*512/4;  cvt_k<<<(n4+255)/256,256,0,stream>>>(oW, oWb, n4); }
  { int n4 = NLAYER*2048*512/4; cvt_k<<<(n4+255)/256,256,0,stream>>>(f1W, f1Wb, n4); }
  { int n4 = NLAYER*512*2048/4; cvt_k<<<(n4+255)/256,256,0,stream>>>(f2W, f2Wb, n4); }
  cvt_pre_k<<<(512*320+255)/256,256,0,stream>>>(preW, preWb);

  // preproc + pre-projection + assemble h
  prep_k<<<MX,128,0,stream>>>(x, feats, out + 2048);
  gemm_k<64,64,false,false,true><<<(MX/128)*8,256,0,stream>>>(feats, preWb, preb, nullptr, t1, 512, 320, 8);
  assemble_k<<<(MPAD*512)/256,256,0,stream>>>(t1, cls, h, hb);

  for (int l = 0; l < NLAYER; ++l){
    gemm_k<128,64,false,true,false><<<(MPAD/128)*12,256,0,stream>>>(hb, ipWb + (size_t)l*1536*512, ipb + l*1536, qkvb, nullptr, 1536, 512, 12);
    attn_win_k<<<(BB*HH*1024)/32,256,0,stream>>>(qkvb, aob);
    attn_last1_k<<<(BB*HH*NCHUNK)/4,256,0,stream>>>(qkvb, pm, pl, po);
    attn_last2_k<<<(BB*HH)/4,256,0,stream>>>(pm, pl, po, aob);
    gemm_k<64,128,false,false,true><<<(MPAD/128)*8,256,0,stream>>>(aob, oWb + (size_t)l*512*512, ob + l*512, nullptr, t1, 512, 512, 8);
    addln_k<<<MPAD/4,256,0,stream>>>(h, t1, ln1w + l*512, ln1b + l*512, hb);
    gemm_k<128,64,true,true,false><<<(MPAD/128)*16,256,0,stream>>>(hb, f1Wb + (size_t)l*2048*512, f1b + l*2048, ffb, nullptr, 2048, 512, 16);
    gemm_k<64,128,false,false,true><<<(MPAD/128)*8,256,0,stream>>>(ffb, f2Wb + (size_t)l*512*2048, f2b + l*512, nullptr, t1, 512, 2048, 8);
    addln_k<<<MPAD/4,256,0,stream>>>(h, t1, ln2w + l*512, ln2b + l*512, hb);
  }

  voice_k<<<512,256,0,stream>>>(h, voiceW, voiceb, out);
  phon_k<<<4096,256,0,stream>>>(h, phonW, phonb, out + 2048 + 16384);
}

// Round 14
// 1699.582 us; speedup vs baseline: 1.7015x; 1.0311x over previous
//
#include <hip/hip_runtime.h>

typedef unsigned short u16;
typedef __bf16 bf16x8 __attribute__((ext_vector_type(8)));
typedef float f32x4 __attribute__((ext_vector_type(4)));

#define DEVINL __device__ __forceinline__

DEVINL float bf2f(u16 u){ union{unsigned u32; float f;} v; v.u32=(unsigned)u<<16; return v.f; }
DEVINL u16 f2bf(float f){ union{float f; unsigned u;} v; v.f=f; return (u16)((v.u + 0x7FFFu + ((v.u>>16)&1u))>>16); }

DEVINL void gload16(const u16* g, u16* l){
  __builtin_amdgcn_global_load_lds((const __attribute__((address_space(1))) void*)g,
                                   (__attribute__((address_space(3))) void*)l, 16, 0, 0);
}

// dims
#define BB 16
#define TT 1024
#define SS 1025
#define DD 512
#define HH 8
#define FFD 2048
#define NLAYER 6
#define MROWS (BB*SS)      // 16400
#define MPAD  16512        // 129*128
#define MX    (BB*TT)      // 16384
#define NCHUNK 17          // ceil(1025/64)

// ---------------- weight conversion ----------------
__global__ __launch_bounds__(256) void cvt_k(const float* __restrict__ in, u16* __restrict__ out, int n4){
  int i = blockIdx.x*256 + threadIdx.x;
  if (i < n4){
    const float4 v = ((const float4*)in)[i];
    ushort4 o; o.x=f2bf(v.x); o.y=f2bf(v.y); o.z=f2bf(v.z); o.w=f2bf(v.w);
    ((ushort4*)out)[i] = o;
  }
}

__global__ __launch_bounds__(256) void cvt_pre_k(const float* __restrict__ in, u16* __restrict__ out){
  int i = blockIdx.x*256 + threadIdx.x; // 512*320
  if (i < 512*320){
    int r = i / 320, c = i - r*320;
    out[i] = (c < 306) ? f2bf(in[r*306 + c]) : (u16)0;
  }
}

// ---------------- preproc: build feats (bf16, 16384 x 320), emit pitch ----------------
__global__ __launch_bounds__(128) void prep_k(const float* __restrict__ x, u16* __restrict__ feats, float* __restrict__ pitch_out){
  int row = blockIdx.x;            // 0..16383  (b*1024 + t)
  int t = row & 1023;
  const float* xr = x + (size_t)row*291;
  float pitch = xr[0];
  if (threadIdx.x == 0) pitch_out[row] = pitch;
  for (int c = threadIdx.x; c < 320; c += 128){
    float v;
    if (c < 290) v = xr[1+c];
    else if (c < 306){
      int i = (c < 298) ? (c-290) : (c-298);
      float base = (c < 298) ? pitch : (float)t;
      int fi = i & 3;
      float f = (fi==0)?1.f:(fi==1)?0.1f:(fi==2)?0.01f:0.001f;
      float a = base * f;
      v = (i < 4) ? sinf(a) : cosf(a);
    }
    else v = 0.f;
    feats[(size_t)row*320 + c] = f2bf(v);
  }
}

// ---------------- assemble h from pre-proj + cls, zero pad rows ----------------
__global__ __launch_bounds__(256) void assemble_k(const float* __restrict__ t1, const float* __restrict__ cls,
                                                  float* __restrict__ h, u16* __restrict__ hb){
  int idx = blockIdx.x*256 + threadIdx.x;
  if (idx >= MPAD*DD) return;
  int r = idx >> 9, d = idx & 511;
  float v = 0.f;
  if (r < MROWS){
    int b = r / 1025, s = r - b*1025;
    v = (s < 1024) ? t1[((size_t)b*1024 + s)*512 + d] : cls[d];
  }
  h[idx] = v; hb[idx] = f2bf(v);
}

// ---------------- GEMM: C[M,N] = A[M,K](bf16) * W[N,K]^T + bias ----------------
// BM=128; BN in {64,128}; BK in {64,128}. XCD-bijective block swizzle (T1).
// T2 swizzle via pre-swizzled global source + swizzled LDS read (LDS linear
// for global_load_lds). BK=128 halves barrier count for BN=64 kernels.
template<int BN, int BK, bool RELU, bool WBF, bool WF32>
__global__ __launch_bounds__(256)
void gemm_k(const u16* __restrict__ A, const u16* __restrict__ W,
            const float* __restrict__ bias, u16* __restrict__ obf,
            float* __restrict__ of32, int N, int K, int gy)
{
  __shared__ u16 As[128*BK];
  __shared__ u16 Ws[BN*BK];
  constexpr int NREP = BN/32;        // col fragments per wave (wave covers BN/2 cols)
  constexpr int KK = BK/32;          // K32 sub-steps per tile
  constexpr int GR = BK/8;           // 16B granules per row
  constexpr int AR = (128*BK)/2048;  // A staging rounds
  constexpr int WR = (BN*BK)/2048;   // W staging rounds
  const int tid = threadIdx.x;
  const int lane = tid & 63, wave = tid >> 6;
  const int wr = wave >> 1, wc = wave & 1;
  const int lr = lane & 15;
  const int x7 = lane & 7;           // == fragment_row & 7 for this lane
  const int gbase = lane >> 4;       // column granule base within K32 block

  // bijective 8-XCD swizzle (m204)
  const int nwg = gridDim.x;
  const int id = blockIdx.x;
  const int q = nwg >> 3, r8 = nwg & 7;
  const int xcd = id & 7, pos = id >> 3;
  const int wgid = (xcd < r8 ? xcd*(q+1) : r8*(q+1) + (xcd-r8)*q) + pos;
  const int bx = wgid / gy, by = wgid - bx*gy;
  const int m0 = bx * 128, n0 = by * BN;

  // swizzled column offsets (elems) for each K32 half
  int colsw[KK];
#pragma unroll
  for (int kk=0; kk<KK; ++kk){
    int gk = kk*4 + gbase;
    colsw[kk] = ((gk & ~7) | ((gk & 7) ^ x7)) * 8;
  }

  int aoff[4], boff[NREP];
#pragma unroll
  for (int i=0;i<4;++i) aoff[i] = (wr*64 + i*16 + lr)*BK;
#pragma unroll
  for (int i=0;i<NREP;++i) boff[i] = (wc*(BN/2) + i*16 + lr)*BK;

  f32x4 acc[4][NREP];
#pragma unroll
  for (int n=0;n<NREP;++n){
    float bv = bias[n0 + wc*(BN/2) + n*16 + lr];
#pragma unroll
    for (int m=0;m<4;++m) acc[m][n] = (f32x4){bv,bv,bv,bv};
  }

  for (int k0=0; k0<K; k0+=BK) {
#pragma unroll
    for (int r=0;r<AR;++r){
      int cb = r*256 + wave*64;
      int chunk = cb + lane;
      int row = chunk / GR, gp = chunk & (GR-1);
      int kc = ((gp & ~7) | ((gp & 7) ^ (row & 7))) * 8;   // pre-swizzled source
      gload16(A + (size_t)(m0+row)*K + k0 + kc, &As[cb*8]);
    }
#pragma unroll
    for (int r=0;r<WR;++r){
      int cb = r*256 + wave*64;
      int chunk = cb + lane;
      int row = chunk / GR, gp = chunk & (GR-1);
      int kc = ((gp & ~7) | ((gp & 7) ^ (row & 7))) * 8;
      gload16(W + (size_t)(n0+row)*K + k0 + kc, &Ws[cb*8]);
    }
    __syncthreads();
#pragma unroll
    for (int kk=0; kk<KK; ++kk){
      bf16x8 af[4], bfr[NREP];
#pragma unroll
      for (int m=0;m<4;++m) af[m] = *(const bf16x8*)&As[aoff[m] + colsw[kk]];
#pragma unroll
      for (int n=0;n<NREP;++n) bfr[n] = *(const bf16x8*)&Ws[boff[n] + colsw[kk]];
#pragma unroll
      for (int m=0;m<4;++m)
#pragma unroll
        for (int n=0;n<NREP;++n)
          acc[m][n] = __builtin_amdgcn_mfma_f32_16x16x32_bf16(af[m], bfr[n], acc[m][n], 0,0,0);
    }
    __syncthreads();
  }

  const int orow = m0 + wr*64 + (lane>>4)*4;
  const int ocol = n0 + wc*(BN/2) + lr;
#pragma unroll
  for (int m=0;m<4;++m)
#pragma unroll
    for (int n=0;n<NREP;++n){
#pragma unroll
      for (int j=0;j<4;++j){
        float v = acc[m][n][j];
        if (RELU) v = fmaxf(v, 0.f);
        size_t idx = (size_t)(orow + m*16 + j) * N + (ocol + n*16);
        if (WBF) obf[idx] = f2bf(v);
        if (WF32) of32[idx] = v;
      }
    }
}

// ---------------- windowed attention: 8 q per wave, 8 lanes per q ----------------
// lane = g*8+e: group g handles q = qb*8+g, elem octet e covers d = e*8..e*8+7.
// 16B loads; 8-lane group reduce = 3 shfl levels (vs 64-lane = 6).
__global__ __launch_bounds__(256) void attn_win_k(const u16* __restrict__ qkv, u16* __restrict__ ao){
  int wid = blockIdx.x*4 + (threadIdx.x>>6);   // 0..16383
  int lane = threadIdx.x & 63;
  int g = lane >> 3, e = lane & 7;
  int bh = wid >> 7, qb = wid & 127;
  int b = bh >> 3, hh = bh & 7;
  int q = qb*8 + g;
  const u16* basep = qkv + (size_t)(b*1025)*1536 + hh*64 + e*8;
  bf16x8 qv8 = *(const bf16x8*)(basep + (size_t)q*1536);
  float qf[8];
#pragma unroll
  for (int i=0;i<8;++i) qf[i] = (float)qv8[i];
  float sc[7];
#pragma unroll
  for (int jj=0;jj<7;++jj){
    int j = q - 3 + jj;
    int jc = min(max(j,0),1024);
    bf16x8 kv8 = *(const bf16x8*)(basep + (size_t)jc*1536 + 512);
    float p = 0.f;
#pragma unroll
    for (int i=0;i<8;++i) p += qf[i]*(float)kv8[i];
    p += __shfl_xor(p,1); p += __shfl_xor(p,2); p += __shfl_xor(p,4);
    sc[jj] = (j>=0 && j<=1024) ? p*0.125f : -1e30f;
  }
  float m = sc[0];
#pragma unroll
  for (int jj=1;jj<7;++jj) m = fmaxf(m, sc[jj]);
  float l = 0.f, pj[7];
#pragma unroll
  for (int jj=0;jj<7;++jj){ pj[jj] = expf(sc[jj]-m); l += pj[jj]; }
  float of[8];
#pragma unroll
  for (int i=0;i<8;++i) of[i] = 0.f;
#pragma unroll
  for (int jj=0;jj<7;++jj){
    int jc = min(max(q-3+jj,0),1024);
    bf16x8 vv8 = *(const bf16x8*)(basep + (size_t)jc*1536 + 1024);
#pragma unroll
    for (int i=0;i<8;++i) of[i] += pj[jj]*(float)vv8[i];
  }
  float inv = 1.f/l;
  uint4 w;
  w.x = (unsigned)f2bf(of[0]*inv) | ((unsigned)f2bf(of[1]*inv)<<16);
  w.y = (unsigned)f2bf(of[2]*inv) | ((unsigned)f2bf(of[3]*inv)<<16);
  w.z = (unsigned)f2bf(of[4]*inv) | ((unsigned)f2bf(of[5]*inv)<<16);
  w.w = (unsigned)f2bf(of[6]*inv) | ((unsigned)f2bf(of[7]*inv)<<16);
  *(uint4*)&ao[((size_t)(b*1025+q))*512 + hh*64 + e*8] = w;
}

// ---------------- last-row attention, pass 1: per-(b,h,chunk) flash partials ----
// 2176 waves (544 blocks x 4): wave = (bh, chunk of <=64 keys); lane = d.
__global__ __launch_bounds__(256) void attn_last1_k(const u16* __restrict__ qkv,
      float* __restrict__ pm, float* __restrict__ pl, float* __restrict__ po){
  int wid = blockIdx.x*4 + (threadIdx.x>>6);   // 0..2175
  int lane = threadIdx.x & 63;
  int bh = wid / NCHUNK, c = wid - bh*NCHUNK;
  int b = bh >> 3, hh = bh & 7;
  size_t base = (size_t)(b*1025)*1536 + hh*64;
  float qv = bf2f(qkv[base + (size_t)1024*1536 + lane]);
  int j0 = c*64, j1 = min(j0+64, 1025);
  float m = -1e30f, l = 0.f, o = 0.f;
  for (int j = j0; j < j1; ++j){
    float kv = bf2f(qkv[base + (size_t)j*1536 + 512 + lane]);
    float vv = bf2f(qkv[base + (size_t)j*1536 + 1024 + lane]);
    float p = qv * kv;
#pragma unroll
    for (int o2=1;o2<64;o2<<=1) p += __shfl_xor(p, o2);
    float s = p * 0.125f;
    float mn = fmaxf(m, s);
    float corr = expf(m - mn);
    float pe = expf(s - mn);
    l = l*corr + pe;
    o = o*corr + pe*vv;
    m = mn;
  }
  if (lane == 0){ pm[wid] = m; pl[wid] = l; }
  po[(size_t)wid*64 + lane] = o;
}

// ---------------- last-row attention, pass 2: merge 17 partials per (b,h) ----
__global__ __launch_bounds__(256) void attn_last2_k(const float* __restrict__ pm,
      const float* __restrict__ pl, const float* __restrict__ po, u16* __restrict__ ao){
  int bh = blockIdx.x*4 + (threadIdx.x>>6);    // 0..127
  int lane = threadIdx.x & 63;
  int b = bh >> 3, hh = bh & 7;
  float M = -1e30f;
#pragma unroll
  for (int c=0;c<NCHUNK;++c) M = fmaxf(M, pm[bh*NCHUNK+c]);
  float L = 0.f, o = 0.f;
#pragma unroll
  for (int c=0;c<NCHUNK;++c){
    float w = expf(pm[bh*NCHUNK+c] - M);
    L += pl[bh*NCHUNK+c]*w;
    o += po[(size_t)(bh*NCHUNK+c)*64 + lane]*w;
  }
  ao[((size_t)(b*1025+1024))*512 + hh*64 + lane] = f2bf(o / L);
}

// ---------------- residual + LayerNorm (row=512), one wave per row ----------------
// t1 is now bf16 (GEMM writes bf16): halves t1 HBM traffic.
__global__ __launch_bounds__(256) void addln_k(float* __restrict__ h, const u16* __restrict__ t1,
      const float* __restrict__ g, const float* __restrict__ be, u16* __restrict__ hb){
  int row = blockIdx.x*4 + (threadIdx.x>>6);
  int lane = threadIdx.x & 63;
  size_t base = (size_t)row*512;
  const float4 a0 = *(const float4*)&h[base + lane*4];
  const float4 a1 = *(const float4*)&h[base + 256 + lane*4];
  const ushort4 tb0 = *(const ushort4*)&t1[base + lane*4];
  const ushort4 tb1 = *(const ushort4*)&t1[base + 256 + lane*4];
  float v[8];
  v[0]=a0.x+bf2f(tb0.x); v[1]=a0.y+bf2f(tb0.y); v[2]=a0.z+bf2f(tb0.z); v[3]=a0.w+bf2f(tb0.w);
  v[4]=a1.x+bf2f(tb1.x); v[5]=a1.y+bf2f(tb1.y); v[6]=a1.z+bf2f(tb1.z); v[7]=a1.w+bf2f(tb1.w);
  float s=0.f, s2=0.f;
#pragma unroll
  for (int i=0;i<8;++i){ s += v[i]; s2 += v[i]*v[i]; }
#pragma unroll
  for (int o2=1;o2<64;o2<<=1){ s += __shfl_xor(s,o2); s2 += __shfl_xor(s2,o2); }
  float mean = s * (1.f/512.f);
  float var = s2 * (1.f/512.f) - mean*mean;
  float inv = rsqrtf(var + 1e-5f);
  const float4 g0 = *(const float4*)&g[lane*4];
  const float4 g1 = *(const float4*)&g[256 + lane*4];
  const float4 e0 = *(const float4*)&be[lane*4];
  const float4 e1 = *(const float4*)&be[256 + lane*4];
  float y[8];
  y[0]=(v[0]-mean)*inv*g0.x+e0.x; y[1]=(v[1]-mean)*inv*g0.y+e0.y;
  y[2]=(v[2]-mean)*inv*g0.z+e0.z; y[3]=(v[3]-mean)*inv*g0.w+e0.w;
  y[4]=(v[4]-mean)*inv*g1.x+e1.x; y[5]=(v[5]-mean)*inv*g1.y+e1.y;
  y[6]=(v[6]-mean)*inv*g1.z+e1.z; y[7]=(v[7]-mean)*inv*g1.w+e1.w;
  float4 o0 = {y[0],y[1],y[2],y[3]}, o1 = {y[4],y[5],y[6],y[7]};
  *(float4*)&h[base + lane*4] = o0;
  *(float4*)&h[base + 256 + lane*4] = o1;
  ushort4 u0, u1;
  u0.x=f2bf(y[0]); u0.y=f2bf(y[1]); u0.z=f2bf(y[2]); u0.w=f2bf(y[3]);
  u1.x=f2bf(y[4]); u1.y=f2bf(y[5]); u1.z=f2bf(y[6]); u1.w=f2bf(y[7]);
  *(ushort4*)&hb[base + lane*4] = u0;
  *(ushort4*)&hb[base + 256 + lane*4] = u1;
}

// ---------------- heads (f32, exact) ----------------
__global__ __launch_bounds__(256) void voice_k(const float* __restrict__ h, const float* __restrict__ W,
                                               const float* __restrict__ bias, float* __restrict__ out){
  int pair = blockIdx.x*4 + (threadIdx.x>>6);   // 0..2047 : b*128 + c
  int lane = threadIdx.x & 63;
  int b = pair >> 7, c = pair & 127;
  const float* hr = h + ((size_t)(b*1025 + 1024))*512;
  const float* wr = W + (size_t)c*512;
  float p = 0.f;
#pragma unroll
  for (int j=0;j<8;++j) p += hr[lane + 64*j]*wr[lane + 64*j];
#pragma unroll
  for (int o2=1;o2<64;o2<<=1) p += __shfl_xor(p,o2);
  if (lane == 0) out[b*128 + c] = p + bias[c];
}

__global__ __launch_bounds__(256) void phon_k(const float* __restrict__ h, const float* __restrict__ W,
                                              const float* __restrict__ bias, float* __restrict__ out){
  int row = blockIdx.x*4 + (threadIdx.x>>6);    // 0..16383 : b*1024 + s
  int lane = threadIdx.x & 63;
  int b = row >> 10, s = row & 1023;
  const float* hr = h + ((size_t)(b*1025 + s))*512;
  float hv[8];
#pragma unroll
  for (int j=0;j<8;++j) hv[j] = hr[lane + 64*j];
#pragma unroll
  for (int c=0;c<10;++c){
    float p = 0.f;
#pragma unroll
    for (int j=0;j<8;++j) p += hv[j]*W[c*512 + lane + 64*j];
#pragma unroll
    for (int o2=1;o2<64;o2<<=1) p += __shfl_xor(p,o2);
    if (lane == c) out[(size_t)row*10 + c] = p + bias[c];
  }
}

extern "C" void kernel_launch(void* const* d_in, const int* in_sizes, int n_in,
                              void* d_out, int out_size, void* d_ws, size_t ws_size,
                              hipStream_t stream) {
  const float* x      = (const float*)d_in[0];
  const float* cls    = (const float*)d_in[1];
  const float* preW   = (const float*)d_in[2];
  const float* preb   = (const float*)d_in[3];
  const float* ipW    = (const float*)d_in[4];
  const float* ipb    = (const float*)d_in[5];
  const float* oW     = (const float*)d_in[6];
  const float* ob     = (const float*)d_in[7];
  const float* f1W    = (const float*)d_in[8];
  const float* f1b    = (const float*)d_in[9];
  const float* f2W    = (const float*)d_in[10];
  const float* f2b    = (const float*)d_in[11];
  const float* ln1w   = (const float*)d_in[12];
  const float* ln1b   = (const float*)d_in[13];
  const float* ln2w   = (const float*)d_in[14];
  const float* ln2b   = (const float*)d_in[15];
  const float* voiceW = (const float*)d_in[16];
  const float* voiceb = (const float*)d_in[17];
  const float* phonW  = (const float*)d_in[18];
  const float* phonb  = (const float*)d_in[19];
  float* out = (float*)d_out;   // [voice 2048 | pitch 16384 | phoneme 163840]

  char* wsp = (char*)d_ws;
  size_t off = 0;
  auto alloc = [&](size_t nbytes)->void*{ void* p = wsp + off; off += (nbytes + 255) & ~(size_t)255; return p; };
  u16* preWb = (u16*)alloc((size_t)512*320*2);
  u16* ipWb  = (u16*)alloc((size_t)NLAYER*1536*512*2);
  u16* oWb   = (u16*)alloc((size_t)NLAYER*512*512*2);
  u16* f1Wb  = (u16*)alloc((size_t)NLAYER*2048*512*2);
  u16* f2Wb  = (u16*)alloc((size_t)NLAYER*512*2048*2);
  u16* feats = (u16*)alloc((size_t)MX*320*2);
  float* h   = (float*)alloc((size_t)MPAD*512*4);
  u16* hb    = (u16*)alloc((size_t)MPAD*512*2);
  u16* qkvb  = (u16*)alloc((size_t)MPAD*1536*2);
  u16* aob   = (u16*)alloc((size_t)MPAD*512*2);
  u16* ffb   = (u16*)alloc((size_t)MPAD*2048*2);
  float* t1  = (float*)alloc((size_t)MPAD*512*4);
  // t1b (bf16 GEMM->addln path) ALIASES t1: t1 f32 is only live pre->assemble.
  u16* t1b   = (u16*)t1;
  // pm/pl/po ALIAS the feats buffer (feats dead after the pre-GEMM;
  // fresh allocations overflowed the 256 MiB workspace -> round-10 abort).
  float* pm  = (float*)feats;                       // 8.7 KB
  float* pl  = pm + (size_t)BB*HH*NCHUNK;           // 8.7 KB
  float* po  = pl + (size_t)BB*HH*NCHUNK;           // 557 KB (total 574 KB << 10.5 MB)

  // weight converts (per-launch: ws is re-poisoned each call)
  { int n4 = NLAYER*1536*512/4; cvt_k<<<(n4+255)/256,256,0,stream>>>(ipW, ipWb, n4); }
  { int n4 = NLAYER*512*512/4;  cvt_k<<<(n4+255)/256,256,0,stream>>>(oW, oWb, n4); }
  { int n4 = NLAYER*2048*512/4; cvt_k<<<(n4+255)/256,256,0,stream>>>(f1W, f1Wb, n4); }
  { int n4 = NLAYER*512*2048/4; cvt_k<<<(n4+255)/256,256,0,stream>>>(f2W, f2Wb, n4); }
  cvt_pre_k<<<(512*320+255)/256,256,0,stream>>>(preW, preWb);

  // preproc + pre-projection + assemble h
  prep_k<<<MX,128,0,stream>>>(x, feats, out + 2048);
  gemm_k<64,64,false,false,true><<<(MX/128)*8,256,0,stream>>>(feats, preWb, preb, nullptr, t1, 512, 320, 8);
  assemble_k<<<(MPAD*512)/256,256,0,stream>>>(t1, cls, h, hb);

  for (int l = 0; l < NLAYER; ++l){
    gemm_k<128,64,false,true,false><<<(MPAD/128)*12,256,0,stream>>>(hb, ipWb + (size_t)l*1536*512, ipb + l*1536, qkvb, nullptr, 1536, 512, 12);
    attn_win_k<<<(BB*HH*1024)/32,256,0,stream>>>(qkvb, aob);
    attn_last1_k<<<(BB*HH*NCHUNK)/4,256,0,stream>>>(qkvb, pm, pl, po);
    attn_last2_k<<<(BB*HH)/4,256,0,stream>>>(pm, pl, po, aob);
    gemm_k<64,128,false,true,false><<<(MPAD/128)*8,256,0,stream>>>(aob, oWb + (size_t)l*512*512, ob + l*512, t1b, nullptr, 512, 512, 8);
    addln_k<<<MPAD/4,256,0,stream>>>(h, t1b, ln1w + l*512, ln1b + l*512, hb);
    gemm_k<128,64,true,true,false><<<(MPAD/128)*16,256,0,stream>>>(hb, f1Wb + (size_t)l*2048*512, f1b + l*2048, ffb, nullptr, 2048, 512, 16);
    gemm_k<64,128,false,true,false><<<(MPAD/128)*8,256,0,stream>>>(ffb, f2Wb + (size_t)l*512*2048, f2b + l*512, t1b, nullptr, 512, 2048, 8);
    addln_k<<<MPAD/4,256,0,stream>>>(h, t1b, ln2w + l*512, ln2b + l*512, hb);
  }

  voice_k<<<512,256,0,stream>>>(h, voiceW, voiceb, out);
  phon_k<<<4096,256,0,stream>>>(h, phonW, phonb, out + 2048 + 16384);
}